// Round 3
// baseline (4870.218 us; speedup 1.0000x reference)
//
#include <hip/hip_runtime.h>
#include <math.h>

constexpr int N_ = 65536;
constexpr int D_ = 64;
constexpr int M_ = 4096;
constexpr float EPS2 = 1.5f;   // candidate window = 2*eps; bf16 dist err bound ~0.6

typedef __attribute__((ext_vector_type(8))) short  short8;  // 8 x bf16 (4 VGPR)
typedef __attribute__((ext_vector_type(4))) float  f32x4;

__device__ inline unsigned long long pack_dl(float d, unsigned m) {
    // dist >= 0 so f32 bits are order-preserving; low word = label (min label on ties)
    return ((unsigned long long)__float_as_uint(d) << 32) | m;
}

__device__ inline unsigned short f2bf(float x) {  // RNE f32 -> bf16 bits
    union { float f; unsigned u; } v; v.f = x;
    return (unsigned short)((v.u + 0x7fffu + ((v.u >> 16) & 1u)) >> 16);
}

// ---------------- prep: f32 -> bf16 (P row-major; C in MFMA-fragment-tiled layout) ----
// ChiT layout: tile t, ks, g4, col, e  ->  ushort offset t*1024 + ks*512 + g4*128 + col*8 + e
__global__ __launch_bounds__(256) void pwd_prep(
        const float* __restrict__ p, const float* __restrict__ c,
        unsigned short* __restrict__ Phi, unsigned short* __restrict__ ChiT) {
    const int tid = blockIdx.x * 256 + threadIdx.x;
    constexpr int PT = N_ * D_ / 8;   // 524288
    constexpr int CT = M_ * D_ / 8;   // 32768
    if (tid < PT) {
        const float4* src = reinterpret_cast<const float4*>(p) + (size_t)tid * 2;
        float4 x = src[0], y = src[1];
        unsigned short o[8] = {f2bf(x.x), f2bf(x.y), f2bf(x.z), f2bf(x.w),
                               f2bf(y.x), f2bf(y.y), f2bf(y.z), f2bf(y.w)};
        *reinterpret_cast<short8*>(Phi + (size_t)tid * 8) =
            *reinterpret_cast<short8*>(o);
    } else if (tid < PT + CT) {
        const int id  = tid - PT;            // id = ((t*2+ks)*4+g4)*16+col
        const int col = id & 15;
        const int g4  = (id >> 4) & 3;
        const int ks  = (id >> 6) & 1;
        const int t   = id >> 7;
        const float* src = c + (size_t)(t * 16 + col) * D_ + ks * 32 + g4 * 8;
        float4 x = *reinterpret_cast<const float4*>(src);
        float4 y = *reinterpret_cast<const float4*>(src + 4);
        unsigned short o[8] = {f2bf(x.x), f2bf(x.y), f2bf(x.z), f2bf(x.w),
                               f2bf(y.x), f2bf(y.y), f2bf(y.z), f2bf(y.w)};
        *reinterpret_cast<short8*>(ChiT + (size_t)id * 8) =
            *reinterpret_cast<short8*>(o);
    }
}

// ---------------- pass A: MFMA approx dists, running min, candidate append ------------
// Wave handles 32 points (2 groups of 16) x all 4096 centroids (256 tiles of 16).
// 16x16x32 bf16 MFMA. Inputs: row/col = lane&15, k-slots = (lane>>4)*8 + e (any HW
// k-permutation cancels since A and B use the same slot mapping). C/D: col = lane&15,
// row = (lane>>4)*4 + reg  [HW-verified m89/m91].
__global__ __launch_bounds__(256) void pwd_approx(
        const float* __restrict__ pn, const float* __restrict__ c_sq,
        const unsigned short* __restrict__ Phi,
        const unsigned short* __restrict__ ChiT,
        unsigned* __restrict__ counter, unsigned* __restrict__ list,
        unsigned long long* __restrict__ results, unsigned cap) {
    const int lane  = threadIdx.x & 63;
    const int wav   = threadIdx.x >> 6;
    const int pbase = blockIdx.x * 128 + wav * 32;
    const int col   = lane & 15;
    const int g4    = lane >> 4;

    short8 afr[2][2];
#pragma unroll
    for (int grp = 0; grp < 2; ++grp)
#pragma unroll
        for (int ks = 0; ks < 2; ++ks)
            afr[grp][ks] = *reinterpret_cast<const short8*>(
                Phi + (size_t)(pbase + grp * 16 + col) * D_ + ks * 32 + g4 * 8);

    float pnv[2][4];
#pragma unroll
    for (int grp = 0; grp < 2; ++grp)
#pragma unroll
        for (int r = 0; r < 4; ++r)
            pnv[grp][r] = pn[pbase + grp * 16 + g4 * 4 + r];

    float    bestd[2][4];
    unsigned bestm[2][4];
    float    thr[2][4];
#pragma unroll
    for (int grp = 0; grp < 2; ++grp)
#pragma unroll
        for (int r = 0; r < 4; ++r) { bestd[grp][r] = INFINITY; bestm[grp][r] = 0; }

    // --- pre-pass on tile 0 (no appends) to establish a finite threshold ---
    {
        const short8 b0 = *reinterpret_cast<const short8*>(ChiT + g4 * 128 + col * 8);
        const short8 b1 = *reinterpret_cast<const short8*>(ChiT + 512 + g4 * 128 + col * 8);
        const float csq = c_sq[col];
        f32x4 acc0 = {0.f, 0.f, 0.f, 0.f}, acc1 = {0.f, 0.f, 0.f, 0.f};
        acc0 = __builtin_amdgcn_mfma_f32_16x16x32_bf16(afr[0][0], b0, acc0, 0, 0, 0);
        acc0 = __builtin_amdgcn_mfma_f32_16x16x32_bf16(afr[0][1], b1, acc0, 0, 0, 0);
        acc1 = __builtin_amdgcn_mfma_f32_16x16x32_bf16(afr[1][0], b0, acc1, 0, 0, 0);
        acc1 = __builtin_amdgcn_mfma_f32_16x16x32_bf16(afr[1][1], b1, acc1, 0, 0, 0);
#pragma unroll
        for (int grp = 0; grp < 2; ++grp)
#pragma unroll
            for (int r = 0; r < 4; ++r) {
                const float accv = (grp == 0) ? acc0[r] : acc1[r];
                const float d = fmaf(-2.f, accv, pnv[grp][r] + csq);
                if (d < bestd[grp][r]) { bestd[grp][r] = d; bestm[grp][r] = col; }
            }
    }
#pragma unroll
    for (int grp = 0; grp < 2; ++grp)
#pragma unroll
        for (int r = 0; r < 4; ++r) {
            float v = bestd[grp][r];
            v = fminf(v, __shfl_xor(v, 1));
            v = fminf(v, __shfl_xor(v, 2));
            v = fminf(v, __shfl_xor(v, 4));
            v = fminf(v, __shfl_xor(v, 8));
            thr[grp][r] = v + EPS2;
        }

#pragma unroll 1
    for (int tile = 0; tile < M_ / 16; ++tile) {
        const int m0 = tile * 16;
        const unsigned short* tb = ChiT + (size_t)tile * 1024;
        const short8 b0 = *reinterpret_cast<const short8*>(tb + g4 * 128 + col * 8);
        const short8 b1 = *reinterpret_cast<const short8*>(tb + 512 + g4 * 128 + col * 8);
        const float csq = c_sq[m0 + col];
        f32x4 acc0 = {0.f, 0.f, 0.f, 0.f}, acc1 = {0.f, 0.f, 0.f, 0.f};
        acc0 = __builtin_amdgcn_mfma_f32_16x16x32_bf16(afr[0][0], b0, acc0, 0, 0, 0);
        acc0 = __builtin_amdgcn_mfma_f32_16x16x32_bf16(afr[0][1], b1, acc0, 0, 0, 0);
        acc1 = __builtin_amdgcn_mfma_f32_16x16x32_bf16(afr[1][0], b0, acc1, 0, 0, 0);
        acc1 = __builtin_amdgcn_mfma_f32_16x16x32_bf16(afr[1][1], b1, acc1, 0, 0, 0);
#pragma unroll
        for (int grp = 0; grp < 2; ++grp)
#pragma unroll
            for (int r = 0; r < 4; ++r) {
                const float accv = (grp == 0) ? acc0[r] : acc1[r];
                const float d = fmaf(-2.f, accv, pnv[grp][r] + csq);
                if (d < bestd[grp][r]) { bestd[grp][r] = d; bestm[grp][r] = m0 + col; }
                const bool hit = d <= thr[grp][r];
                const unsigned long long bits = __ballot(hit);
                if (bits) {  // wave-uniform
                    const int leader = __ffsll((unsigned long long)bits) - 1;
                    unsigned base = 0;
                    if (lane == leader)
                        base = atomicAdd(counter, (unsigned)__popcll(bits));
                    base = (unsigned)__shfl((int)base, leader);
                    if (hit) {
                        const unsigned off =
                            base + (unsigned)__popcll(bits & ((1ull << lane) - 1ull));
                        if (off < cap) {
                            const unsigned pt =
                                (unsigned)(pbase + grp * 16 + g4 * 4 + r);
                            list[off] = (pt << 12) | (unsigned)(m0 + col);
                        }
                    }
                }
            }
        if ((tile & 3) == 3) {  // re-sync thresholds across the 16 col-lanes
#pragma unroll
            for (int grp = 0; grp < 2; ++grp)
#pragma unroll
                for (int r = 0; r < 4; ++r) {
                    float v = bestd[grp][r];
                    v = fminf(v, __shfl_xor(v, 1));
                    v = fminf(v, __shfl_xor(v, 2));
                    v = fminf(v, __shfl_xor(v, 4));
                    v = fminf(v, __shfl_xor(v, 8));
                    thr[grp][r] = v + EPS2;
                }
        }
    }

    // Insurance vs list overflow: approx best with +EPS2 penalty (any exact candidate
    // beats it since EPS2 > true error bound; only decides if appends were dropped).
#pragma unroll
    for (int grp = 0; grp < 2; ++grp)
#pragma unroll
        for (int r = 0; r < 4; ++r) {
            const unsigned pt = (unsigned)(pbase + grp * 16 + g4 * 4 + r);
            atomicMin(&results[pt], pack_dl(bestd[grp][r] + EPS2, bestm[grp][r]));
        }
}

// ---------------- pass B: exact f32 re-eval of candidates (round-2 arithmetic) --------
__global__ __launch_bounds__(256) void pwd_exact(
        const float* __restrict__ p, const float* __restrict__ pn,
        const float* __restrict__ c, const float* __restrict__ c_sq,
        const unsigned* __restrict__ counter, const unsigned* __restrict__ list,
        unsigned long long* __restrict__ results, unsigned cap) {
    unsigned cnt = *counter;
    if (cnt > cap) cnt = cap;
    for (unsigned i = blockIdx.x * 256 + threadIdx.x; i < cnt; i += gridDim.x * 256) {
        const unsigned v = list[i];
        const unsigned n = v >> 12;
        const unsigned m = v & 4095u;
        const float* pr = p + (size_t)n * D_;
        const float* cm = c + (size_t)m * D_;
        float a0 = 0.f, a1 = 0.f, a2 = 0.f, a3 = 0.f;
#pragma unroll
        for (int k = 0; k < D_; k += 4) {
            a0 = fmaf(pr[k + 0], cm[k + 0], a0);
            a1 = fmaf(pr[k + 1], cm[k + 1], a1);
            a2 = fmaf(pr[k + 2], cm[k + 2], a2);
            a3 = fmaf(pr[k + 3], cm[k + 3], a3);
        }
        const float dot  = (a0 + a1) + (a2 + a3);
        const float dist = fmaf(-2.f, dot, pn[n] + c_sq[m]);
        atomicMin(&results[n], pack_dl(dist, m));
    }
}

__global__ __launch_bounds__(256) void pwd_out(
        const unsigned long long* __restrict__ results, float* __restrict__ out) {
    const int n = blockIdx.x * 256 + threadIdx.x;
    const unsigned long long v = results[n];
    out[n]      = __uint_as_float((unsigned)(v >> 32));
    out[N_ + n] = (float)(unsigned)(v & 0xffffffffu);
}

// ---------------- fallback: f32 VALU path (round-2 structure, CHUNKS=8) ---------------
constexpr int FCH = 8;
constexpr int FMC = M_ / FCH;

__global__ __launch_bounds__(256) void pwd_chunk(
        const float* __restrict__ p, const float* __restrict__ pn,
        const float* __restrict__ c, const float* __restrict__ c_sq,
        unsigned long long* __restrict__ ws) {
    const int n = blockIdx.x * 256 + threadIdx.x;
    const int mbase = blockIdx.y * FMC;
    float prr[D_];
    const float4* p4 = reinterpret_cast<const float4*>(p + (size_t)n * D_);
#pragma unroll
    for (int i = 0; i < D_ / 4; ++i) {
        float4 v = p4[i];
        prr[4 * i + 0] = v.x; prr[4 * i + 1] = v.y;
        prr[4 * i + 2] = v.z; prr[4 * i + 3] = v.w;
    }
    const float pnn = pn[n];
    float bestD = INFINITY;
    int   bestM = mbase;
#pragma unroll 2
    for (int mi = 0; mi < FMC; ++mi) {
        const int m = mbase + mi;
        const float* cm = c + (size_t)m * D_;
        float a0 = 0.f, a1 = 0.f, a2 = 0.f, a3 = 0.f;
#pragma unroll
        for (int k = 0; k < D_; k += 4) {
            a0 = fmaf(prr[k + 0], cm[k + 0], a0);
            a1 = fmaf(prr[k + 1], cm[k + 1], a1);
            a2 = fmaf(prr[k + 2], cm[k + 2], a2);
            a3 = fmaf(prr[k + 3], cm[k + 3], a3);
        }
        const float dot  = (a0 + a1) + (a2 + a3);
        const float dist = fmaf(-2.f, dot, pnn + c_sq[m]);
        if (dist < bestD) { bestD = dist; bestM = m; }
    }
    atomicMin(&ws[n], pack_dl(bestD, (unsigned)bestM));
}

extern "C" void kernel_launch(void* const* d_in, const int* in_sizes, int n_in,
                              void* d_out, int out_size, void* d_ws, size_t ws_size,
                              hipStream_t stream) {
    const float* p    = (const float*)d_in[0];   // [N, D]
    const float* pn   = (const float*)d_in[1];   // [N]
    const float* c    = (const float*)d_in[2];   // [M, D]
    const float* c_sq = (const float*)d_in[3];   // [M]
    float* out = (float*)d_out;

    char* ws = (char*)d_ws;
    const size_t sz_res   = (size_t)N_ * 8;         // 512 KB packed results
    const size_t off_cnt  = sz_res;
    const size_t off_list = off_cnt + 256;
    const size_t sz_phi   = (size_t)N_ * D_ * 2;    // 8 MB
    const size_t sz_chi   = (size_t)M_ * D_ * 2;    // 512 KB

    size_t cap = 0;
    if (ws_size > off_list + sz_phi + sz_chi) {
        cap = (ws_size - off_list - sz_phi - sz_chi) / 4;
        if (cap > 6ull * 1024 * 1024) cap = 6ull * 1024 * 1024;
        cap &= ~(size_t)63;
    }

    if (cap >= 2ull * 1024 * 1024) {
        unsigned*           counter = (unsigned*)(ws + off_cnt);
        unsigned*           list    = (unsigned*)(ws + off_list);
        unsigned short*     Phi     = (unsigned short*)(ws + off_list + cap * 4);
        unsigned short*     ChiT    = (unsigned short*)(ws + off_list + cap * 4 + sz_phi);
        unsigned long long* results = (unsigned long long*)ws;

        hipMemsetAsync(ws, 0xFF, sz_res, stream);
        hipMemsetAsync(ws + off_cnt, 0, 16, stream);
        pwd_prep<<<(N_ * D_ / 8 + M_ * D_ / 8 + 255) / 256, 256, 0, stream>>>(p, c, Phi, ChiT);
        pwd_approx<<<N_ / 128, 256, 0, stream>>>(pn, c_sq, Phi, ChiT,
                                                 counter, list, results, (unsigned)cap);
        pwd_exact<<<2048, 256, 0, stream>>>(p, pn, c, c_sq,
                                            counter, list, results, (unsigned)cap);
        pwd_out<<<N_ / 256, 256, 0, stream>>>(results, out);
    } else {
        // fallback: f32 VALU path
        unsigned long long* results = (unsigned long long*)ws;
        hipMemsetAsync(ws, 0xFF, sz_res, stream);
        dim3 grid(N_ / 256, FCH);
        pwd_chunk<<<grid, 256, 0, stream>>>(p, pn, c, c_sq, results);
        pwd_out<<<N_ / 256, 256, 0, stream>>>(results, out);
    }
}

// Round 5
// 709.831 us; speedup vs baseline: 6.8611x; 6.8611x over previous
//
#include <hip/hip_runtime.h>
#include <math.h>

constexpr int N_ = 65536;
constexpr int D_ = 64;
constexpr int M_ = 4096;

typedef __attribute__((ext_vector_type(8))) short  short8;  // 8 x bf16 (4 VGPR)
typedef __attribute__((ext_vector_type(4))) float  f32x4;

__device__ inline unsigned long long pack_dl(float d, unsigned m) {
    // dist >= 0 so f32 bits are order-preserving; low word = label (min label on ties)
    return ((unsigned long long)__float_as_uint(d) << 32) | m;
}

__device__ inline unsigned short f2bf(float x) {  // RNE f32 -> bf16 bits
    union { float f; unsigned u; } v; v.f = x;
    return (unsigned short)((v.u + 0x7fffu + ((v.u >> 16) & 1u)) >> 16);
}

// ---------------- prep: bf16 casts + fragment-tiled C + (-0.5*c_sq) ----------------
// ChiT layout: tile t, ks, g4, col, e -> ushort off t*1024 + ks*512 + g4*128 + col*8 + e
__global__ __launch_bounds__(256) void pwd_prep(
        const float* __restrict__ p, const float* __restrict__ c,
        const float* __restrict__ c_sq,
        unsigned short* __restrict__ Phi, unsigned short* __restrict__ ChiT,
        float* __restrict__ nhcsq) {
    const int tid = blockIdx.x * 256 + threadIdx.x;
    constexpr int PT = N_ * D_ / 8;   // 524288
    constexpr int CT = M_ * D_ / 8;   // 32768
    if (tid < PT) {
        const float4* src = reinterpret_cast<const float4*>(p) + (size_t)tid * 2;
        float4 x = src[0], y = src[1];
        unsigned short o[8] = {f2bf(x.x), f2bf(x.y), f2bf(x.z), f2bf(x.w),
                               f2bf(y.x), f2bf(y.y), f2bf(y.z), f2bf(y.w)};
        *reinterpret_cast<short8*>(Phi + (size_t)tid * 8) =
            *reinterpret_cast<short8*>(o);
    } else if (tid < PT + CT) {
        const int id  = tid - PT;            // id = ((t*2+ks)*4+g4)*16+col
        const int col = id & 15;
        const int g4  = (id >> 4) & 3;
        const int ks  = (id >> 6) & 1;
        const int t   = id >> 7;
        const float* src = c + (size_t)(t * 16 + col) * D_ + ks * 32 + g4 * 8;
        float4 x = *reinterpret_cast<const float4*>(src);
        float4 y = *reinterpret_cast<const float4*>(src + 4);
        unsigned short o[8] = {f2bf(x.x), f2bf(x.y), f2bf(x.z), f2bf(x.w),
                               f2bf(y.x), f2bf(y.y), f2bf(y.z), f2bf(y.w)};
        *reinterpret_cast<short8*>(ChiT + (size_t)id * 8) =
            *reinterpret_cast<short8*>(o);
    } else if (tid < PT + CT + M_) {
        const int m = tid - PT - CT;
        nhcsq[m] = -0.5f * c_sq[m];
    }
}

// Branchless sorted-descending top-4 insert (scores: bigger = closer centroid).
__device__ inline void ins4(float (&s)[4], unsigned (&m)[4], float v, unsigned lbl) {
    const bool c0 = v > s[0], c1 = v > s[1], c2 = v > s[2], c3 = v > s[3];
    s[3] = c3 ? (c2 ? s[2] : v) : s[3];  m[3] = c3 ? (c2 ? m[2] : lbl) : m[3];
    s[2] = c2 ? (c1 ? s[1] : v) : s[2];  m[2] = c2 ? (c1 ? m[1] : lbl) : m[2];
    s[1] = c1 ? (c0 ? s[0] : v) : s[1];  m[1] = c1 ? (c0 ? m[0] : lbl) : m[1];
    s[0] = c0 ? v : s[0];                m[0] = c0 ? lbl : m[0];
}

// ---------------- pass A: MFMA scores, lane-local top-4, no atomics ----------------
// mfma(A=centroid tile, B=point tile): D row=(lane>>4)*4+reg = centroid, col=lane&15
// = point [HW-verified m89/m91 + round-3 absmax 0.0]. acc init = -0.5*||c||^2 so
// score = dot - csq/2; dist = pn - 2*score (pn constant per point -> ignored).
constexpr int GRPS = 2;                       // 32 points per wave
__global__ __launch_bounds__(256) void pwd_scan(
        const unsigned short* __restrict__ Phi,
        const unsigned short* __restrict__ ChiT,
        const float* __restrict__ nhcsq,
        unsigned short* __restrict__ cand) {
    const int lane  = threadIdx.x & 63;
    const int wav   = threadIdx.x >> 6;
    const int pbase = blockIdx.x * (4 * GRPS * 16) + wav * (GRPS * 16);
    const int col   = lane & 15;
    const int g4    = lane >> 4;

    short8 bfr[GRPS][2];
#pragma unroll
    for (int g = 0; g < GRPS; ++g)
#pragma unroll
        for (int ks = 0; ks < 2; ++ks)
            bfr[g][ks] = *reinterpret_cast<const short8*>(
                Phi + (size_t)(pbase + g * 16 + col) * D_ + ks * 32 + g4 * 8);

    float    s[GRPS][4];
    unsigned ml[GRPS][4];
#pragma unroll
    for (int g = 0; g < GRPS; ++g)
#pragma unroll
        for (int j = 0; j < 4; ++j) { s[g][j] = -INFINITY; ml[g][j] = 0; }

#pragma unroll 2
    for (int tile = 0; tile < M_ / 16; ++tile) {
        const unsigned short* tb = ChiT + (size_t)tile * 1024;
        const short8 a0 = *reinterpret_cast<const short8*>(tb + g4 * 128 + col * 8);
        const short8 a1 = *reinterpret_cast<const short8*>(tb + 512 + g4 * 128 + col * 8);
        const float4 q  = *reinterpret_cast<const float4*>(nhcsq + tile * 16 + g4 * 4);
        const unsigned mb = (unsigned)(tile * 16 + g4 * 4);
#pragma unroll
        for (int g = 0; g < GRPS; ++g) {
            f32x4 acc = {q.x, q.y, q.z, q.w};
            acc = __builtin_amdgcn_mfma_f32_16x16x32_bf16(a0, bfr[g][0], acc, 0, 0, 0);
            acc = __builtin_amdgcn_mfma_f32_16x16x32_bf16(a1, bfr[g][1], acc, 0, 0, 0);
#pragma unroll
            for (int r = 0; r < 4; ++r)
                ins4(s[g], ml[g], acc[r], mb + r);
        }
    }

    // write 4 candidate labels per lane per group: cand[point*16 + g4*4 .. +3]
#pragma unroll
    for (int g = 0; g < GRPS; ++g) {
        uint2 w;
        w.x = (ml[g][0] & 0xffffu) | (ml[g][1] << 16);
        w.y = (ml[g][2] & 0xffffu) | (ml[g][3] << 16);
        *reinterpret_cast<uint2*>(
            cand + (size_t)(pbase + g * 16 + col) * 16 + g4 * 4) = w;
    }
}

// ---------------- pass B: exact f32 re-eval of 16 candidates (round-2 arithmetic) ----
__global__ __launch_bounds__(256) void pwd_exact(
        const float* __restrict__ p, const float* __restrict__ pn,
        const float* __restrict__ c, const float* __restrict__ c_sq,
        const unsigned short* __restrict__ cand, float* __restrict__ out) {
    const int n = blockIdx.x * 256 + threadIdx.x;
    float pr[D_];
    const float4* p4 = reinterpret_cast<const float4*>(p + (size_t)n * D_);
#pragma unroll
    for (int i = 0; i < D_ / 4; ++i) {
        float4 v = p4[i];
        pr[4 * i + 0] = v.x; pr[4 * i + 1] = v.y;
        pr[4 * i + 2] = v.z; pr[4 * i + 3] = v.w;
    }
    const float pnn = pn[n];

    const uint4* cw = reinterpret_cast<const uint4*>(cand + (size_t)n * 16);
    uint4 w0 = cw[0], w1 = cw[1];
    unsigned ww[8] = {w0.x, w0.y, w0.z, w0.w, w1.x, w1.y, w1.z, w1.w};

    unsigned long long best = ~0ull;
#pragma unroll 2
    for (int j = 0; j < 16; ++j) {
        const unsigned m = (ww[j >> 1] >> ((j & 1) * 16)) & 0xffffu;
        const float* cm = c + (size_t)m * D_;
        float a0 = 0.f, a1 = 0.f, a2 = 0.f, a3 = 0.f;
#pragma unroll
        for (int k = 0; k < D_; k += 4) {
            a0 = fmaf(pr[k + 0], cm[k + 0], a0);
            a1 = fmaf(pr[k + 1], cm[k + 1], a1);
            a2 = fmaf(pr[k + 2], cm[k + 2], a2);
            a3 = fmaf(pr[k + 3], cm[k + 3], a3);
        }
        const float dot  = (a0 + a1) + (a2 + a3);
        const float dist = fmaf(-2.f, dot, pnn + c_sq[m]);
        const unsigned long long key = pack_dl(dist, m);
        best = key < best ? key : best;
    }
    out[n]      = __uint_as_float((unsigned)(best >> 32));
    out[N_ + n] = (float)(unsigned)(best & 0xffffffffu);
}

// ---------------- fallback: f32 VALU path (round-2 structure) ----------------------
constexpr int FCH = 8;
constexpr int FMC = M_ / FCH;

__global__ __launch_bounds__(256) void pwd_chunk(
        const float* __restrict__ p, const float* __restrict__ pn,
        const float* __restrict__ c, const float* __restrict__ c_sq,
        unsigned long long* __restrict__ ws) {
    const int n = blockIdx.x * 256 + threadIdx.x;
    const int mbase = blockIdx.y * FMC;
    float prr[D_];
    const float4* p4 = reinterpret_cast<const float4*>(p + (size_t)n * D_);
#pragma unroll
    for (int i = 0; i < D_ / 4; ++i) {
        float4 v = p4[i];
        prr[4 * i + 0] = v.x; prr[4 * i + 1] = v.y;
        prr[4 * i + 2] = v.z; prr[4 * i + 3] = v.w;
    }
    const float pnn = pn[n];
    float bestD = INFINITY;
    int   bestM = mbase;
#pragma unroll 2
    for (int mi = 0; mi < FMC; ++mi) {
        const int m = mbase + mi;
        const float* cm = c + (size_t)m * D_;
        float a0 = 0.f, a1 = 0.f, a2 = 0.f, a3 = 0.f;
#pragma unroll
        for (int k = 0; k < D_; k += 4) {
            a0 = fmaf(prr[k + 0], cm[k + 0], a0);
            a1 = fmaf(prr[k + 1], cm[k + 1], a1);
            a2 = fmaf(prr[k + 2], cm[k + 2], a2);
            a3 = fmaf(prr[k + 3], cm[k + 3], a3);
        }
        const float dot  = (a0 + a1) + (a2 + a3);
        const float dist = fmaf(-2.f, dot, pnn + c_sq[m]);
        if (dist < bestD) { bestD = dist; bestM = m; }
    }
    atomicMin(&ws[n], pack_dl(bestD, (unsigned)bestM));
}

__global__ __launch_bounds__(256) void pwd_out(
        const unsigned long long* __restrict__ results, float* __restrict__ out) {
    const int n = blockIdx.x * 256 + threadIdx.x;
    const unsigned long long v = results[n];
    out[n]      = __uint_as_float((unsigned)(v >> 32));
    out[N_ + n] = (float)(unsigned)(v & 0xffffffffu);
}

extern "C" void kernel_launch(void* const* d_in, const int* in_sizes, int n_in,
                              void* d_out, int out_size, void* d_ws, size_t ws_size,
                              hipStream_t stream) {
    const float* p    = (const float*)d_in[0];   // [N, D]
    const float* pn   = (const float*)d_in[1];   // [N]
    const float* c    = (const float*)d_in[2];   // [M, D]
    const float* c_sq = (const float*)d_in[3];   // [M]
    float* out = (float*)d_out;

    char* ws = (char*)d_ws;
    const size_t off_phi  = 0;
    const size_t off_chi  = (size_t)N_ * D_ * 2;                 // 8 MB
    const size_t off_nhc  = off_chi + (size_t)M_ * D_ * 2;       // +512 KB
    const size_t off_cand = off_nhc + (size_t)M_ * 4;            // +16 KB
    const size_t need     = off_cand + (size_t)N_ * 16 * 2;      // +2 MB

    if (ws_size >= need) {
        unsigned short* Phi   = (unsigned short*)(ws + off_phi);
        unsigned short* ChiT  = (unsigned short*)(ws + off_chi);
        float*          nhcsq = (float*)(ws + off_nhc);
        unsigned short* cand  = (unsigned short*)(ws + off_cand);

        constexpr int PREP_T = N_ * D_ / 8 + M_ * D_ / 8 + M_;
        pwd_prep<<<(PREP_T + 255) / 256, 256, 0, stream>>>(p, c, c_sq, Phi, ChiT, nhcsq);
        pwd_scan<<<N_ / (4 * GRPS * 16), 256, 0, stream>>>(Phi, ChiT, nhcsq, cand);
        pwd_exact<<<N_ / 256, 256, 0, stream>>>(p, pn, c, c_sq, cand, out);
    } else if (ws_size >= (size_t)N_ * 8) {
        unsigned long long* results = (unsigned long long*)ws;
        hipMemsetAsync(ws, 0xFF, (size_t)N_ * 8, stream);
        dim3 grid(N_ / 256, FCH);
        pwd_chunk<<<grid, 256, 0, stream>>>(p, pn, c, c_sq, results);
        pwd_out<<<N_ / 256, 256, 0, stream>>>(results, out);
    }
}

// Round 7
// 227.229 us; speedup vs baseline: 21.4331x; 3.1239x over previous
//
#include <hip/hip_runtime.h>
#include <math.h>

constexpr int N_ = 65536;
constexpr int D_ = 64;
constexpr int M_ = 4096;
constexpr int HT = 128;            // tiles per M-half (M/2/16)
constexpr int GT = 4;              // tiles per staged LDS group (8 KB)
constexpr int NG = HT / GT;        // 32 groups per half

typedef __attribute__((ext_vector_type(8))) short  short8;  // 8 x bf16
typedef __attribute__((ext_vector_type(4))) float  f32x4;

__device__ inline unsigned long long pack_dl(float d, unsigned m) {
    return ((unsigned long long)__float_as_uint(d) << 32) | m;
}
__device__ inline unsigned short f2bf(float x) {  // RNE f32 -> bf16 bits
    union { float f; unsigned u; } v; v.f = x;
    return (unsigned short)((v.u + 0x7fffu + ((v.u >> 16) & 1u)) >> 16);
}

// ---------------- prep: bf16 casts + fragment-tiled C + (-0.5*c_sq) ----------------
// ChiT: tile t, ks, g4, col, e -> ushort off t*1024 + ks*512 + g4*128 + col*8 + e
__global__ __launch_bounds__(256) void pwd_prep(
        const float* __restrict__ p, const float* __restrict__ c,
        const float* __restrict__ c_sq,
        unsigned short* __restrict__ Phi, unsigned short* __restrict__ ChiT,
        float* __restrict__ nhcsq) {
    const int tid = blockIdx.x * 256 + threadIdx.x;
    constexpr int PT = N_ * D_ / 8;
    constexpr int CT = M_ * D_ / 8;
    if (tid < PT) {
        const float4* src = reinterpret_cast<const float4*>(p) + (size_t)tid * 2;
        float4 x = src[0], y = src[1];
        unsigned short o[8] = {f2bf(x.x), f2bf(x.y), f2bf(x.z), f2bf(x.w),
                               f2bf(y.x), f2bf(y.y), f2bf(y.z), f2bf(y.w)};
        *reinterpret_cast<short8*>(Phi + (size_t)tid * 8) = *reinterpret_cast<short8*>(o);
    } else if (tid < PT + CT) {
        const int id  = tid - PT;
        const int col = id & 15;
        const int g4  = (id >> 4) & 3;
        const int ks  = (id >> 6) & 1;
        const int t   = id >> 7;
        const float* src = c + (size_t)(t * 16 + col) * D_ + ks * 32 + g4 * 8;
        float4 x = *reinterpret_cast<const float4*>(src);
        float4 y = *reinterpret_cast<const float4*>(src + 4);
        unsigned short o[8] = {f2bf(x.x), f2bf(x.y), f2bf(x.z), f2bf(x.w),
                               f2bf(y.x), f2bf(y.y), f2bf(y.z), f2bf(y.w)};
        *reinterpret_cast<short8*>(ChiT + (size_t)id * 8) = *reinterpret_cast<short8*>(o);
    } else if (tid < PT + CT + M_) {
        const int m = tid - PT - CT;
        nhcsq[m] = -0.5f * c_sq[m];
    }
}

// ---------------- pass A: LDS-pipelined MFMA scan, top-2 per (g4, r-pair) ----------
// mfma(A=centroid fragment, B=point fragment): D row=(lane>>4)*4+reg = centroid,
// col=lane&15 = point [HW-verified + rounds 3/5 absmax 0.0]. score = dot - csq/2.
__global__ __launch_bounds__(256) void pwd_scan(
        const unsigned short* __restrict__ Phi,
        const unsigned short* __restrict__ ChiT,
        const float* __restrict__ nhcsq,
        unsigned short* __restrict__ cand) {
    __shared__ __align__(16) char  lds_chi[2][GT * 2048];  // 2 x 8 KB
    __shared__ __align__(16) float nh_lds[2048];           // 8 KB (this half)

    const int tid  = threadIdx.x;
    const int lane = tid & 63;
    const int wav  = tid >> 6;
    const int col  = lane & 15;
    const int g4   = lane >> 4;
    const int half = blockIdx.y;
    const int pbase = blockIdx.x * 128 + wav * 32;

    // stage -0.5*c_sq (this half) into LDS
    {
        const float4* src = reinterpret_cast<const float4*>(nhcsq + half * 2048);
        reinterpret_cast<float4*>(nh_lds)[tid]       = src[tid];
        reinterpret_cast<float4*>(nh_lds)[tid + 256] = src[tid + 256];
    }

    // point fragments (B operand), held in registers
    short8 bfr[2][2];
#pragma unroll
    for (int g = 0; g < 2; ++g)
#pragma unroll
        for (int ks = 0; ks < 2; ++ks)
            bfr[g][ks] = *reinterpret_cast<const short8*>(
                Phi + (size_t)(pbase + g * 16 + col) * D_ + ks * 32 + g4 * 8);

    // trackers: top-2 per (group g, r-pair tr)
    float    s0[2][2], s1v[2][2];
    unsigned m0[2][2], m1v[2][2];
#pragma unroll
    for (int g = 0; g < 2; ++g)
#pragma unroll
        for (int tr = 0; tr < 2; ++tr) {
            s0[g][tr] = -INFINITY; s1v[g][tr] = -INFINITY;
            m0[g][tr] = 0;         m1v[g][tr] = 0;
        }

    const char* gchi = reinterpret_cast<const char*>(ChiT) + (size_t)half * HT * 2048;

#define STAGE_LOAD(R0, R1, grp)                                                  \
    R0 = *reinterpret_cast<const float4*>(gchi + (size_t)(grp) * (GT*2048) + tid*16);        \
    R1 = *reinterpret_cast<const float4*>(gchi + (size_t)(grp) * (GT*2048) + 4096 + tid*16);

#define STAGE_WRITE(BUF, R0, R1)                                                 \
    *reinterpret_cast<float4*>(lds_chi[BUF] + tid*16)        = R0;               \
    *reinterpret_cast<float4*>(lds_chi[BUF] + 4096 + tid*16) = R1;

#define COMPUTE_GROUP(BUF, grp)                                                  \
    _Pragma("unroll")                                                            \
    for (int t = 0; t < GT; ++t) {                                               \
        const char* tb = lds_chi[BUF] + t * 2048;                                \
        const short8 a0 = *reinterpret_cast<const short8*>(tb + g4*256 + col*16);\
        const short8 a1 = *reinterpret_cast<const short8*>(tb + 1024 + g4*256 + col*16); \
        const int tg = (grp) * GT + t;                                           \
        const float4 q = *reinterpret_cast<const float4*>(nh_lds + tg*16 + g4*4);\
        const unsigned mb = (unsigned)(half * 2048 + tg * 16 + g4 * 4);          \
        _Pragma("unroll")                                                        \
        for (int g = 0; g < 2; ++g) {                                            \
            f32x4 acc = {q.x, q.y, q.z, q.w};                                    \
            acc = __builtin_amdgcn_mfma_f32_16x16x32_bf16(a0, bfr[g][0], acc, 0, 0, 0); \
            acc = __builtin_amdgcn_mfma_f32_16x16x32_bf16(a1, bfr[g][1], acc, 0, 0, 0); \
            _Pragma("unroll")                                                    \
            for (int r = 0; r < 4; ++r) {                                        \
                const int tr = r >> 1;                                           \
                const float v = acc[r];                                          \
                const unsigned lbl = mb + r;                                     \
                const bool c0 = v > s0[g][tr], c1 = v > s1v[g][tr];              \
                s1v[g][tr] = c1 ? (c0 ? s0[g][tr] : v)   : s1v[g][tr];           \
                m1v[g][tr] = c1 ? (c0 ? m0[g][tr] : lbl) : m1v[g][tr];           \
                s0[g][tr]  = c0 ? v   : s0[g][tr];                               \
                m0[g][tr]  = c0 ? lbl : m0[g][tr];                               \
            }                                                                    \
        }                                                                        \
    }

    float4 rA0, rA1, rB0, rB1;
    STAGE_LOAD(rA0, rA1, 0)
    __syncthreads();  // nh_lds ready

#pragma unroll 1
    for (int gp = 0; gp < NG; gp += 2) {
        STAGE_WRITE(0, rA0, rA1)
        __syncthreads();
        STAGE_LOAD(rB0, rB1, gp + 1)       // prefetch under compute
        COMPUTE_GROUP(0, gp)

        STAGE_WRITE(1, rB0, rB1)
        __syncthreads();
        if (gp + 2 < NG) { STAGE_LOAD(rA0, rA1, gp + 2) }
        COMPUTE_GROUP(1, gp + 1)
    }

    // write 4 labels per lane per group: uint2 at cand[(half*N + pt)*16 + g4*4]
#pragma unroll
    for (int g = 0; g < 2; ++g) {
        const int pt = pbase + g * 16 + col;
        uint2 w;
        w.x = (m0[g][0] & 0xffffu) | (m1v[g][0] << 16);
        w.y = (m0[g][1] & 0xffffu) | (m1v[g][1] << 16);
        *reinterpret_cast<uint2*>(cand + ((size_t)(half * N_ + pt) * 16 + g4 * 4)) = w;
    }
#undef STAGE_LOAD
#undef STAGE_WRITE
#undef COMPUTE_GROUP
}

// ---------------- pass B: exact f32 re-eval, 4 threads/point x 8 candidates --------
__global__ __launch_bounds__(256) void pwd_exact(
        const float* __restrict__ p, const float* __restrict__ pn,
        const float* __restrict__ c, const float* __restrict__ c_sq,
        const unsigned short* __restrict__ cand, float* __restrict__ out) {
    const int t  = blockIdx.x * 256 + threadIdx.x;
    const int pt = t >> 2, j = t & 3;

    float pr[D_];
    const float4* p4 = reinterpret_cast<const float4*>(p + (size_t)pt * D_);
#pragma unroll
    for (int i = 0; i < D_ / 4; ++i) {
        float4 v = p4[i];
        pr[4*i+0] = v.x; pr[4*i+1] = v.y; pr[4*i+2] = v.z; pr[4*i+3] = v.w;
    }
    const float pnn = pn[pt];
    const uint2* cu = reinterpret_cast<const uint2*>(cand);

    unsigned long long best = ~0ull;
#pragma unroll
    for (int h = 0; h < 2; ++h) {
        const uint2 w = cu[(size_t)(h * N_ + pt) * 4 + j];
        const unsigned lbls[4] = {w.x & 0xffffu, w.x >> 16, w.y & 0xffffu, w.y >> 16};
#pragma unroll
        for (int jj = 0; jj < 4; ++jj) {
            const unsigned m = lbls[jj];
            const float* cm = c + (size_t)m * D_;
            float a0 = 0.f, a1 = 0.f, a2 = 0.f, a3 = 0.f;
#pragma unroll
            for (int k = 0; k < D_; k += 4) {   // round-2 canonical arithmetic
                a0 = fmaf(pr[k+0], cm[k+0], a0);
                a1 = fmaf(pr[k+1], cm[k+1], a1);
                a2 = fmaf(pr[k+2], cm[k+2], a2);
                a3 = fmaf(pr[k+3], cm[k+3], a3);
            }
            const float dot  = (a0 + a1) + (a2 + a3);
            const float dist = fmaf(-2.f, dot, pnn + c_sq[m]);
            const unsigned long long key = pack_dl(dist, m);
            best = key < best ? key : best;
        }
    }
    unsigned long long o1 = __shfl_xor(best, 1); best = o1 < best ? o1 : best;
    unsigned long long o2 = __shfl_xor(best, 2); best = o2 < best ? o2 : best;
    if (j == 0) {
        out[pt]      = __uint_as_float((unsigned)(best >> 32));
        out[N_ + pt] = (float)(unsigned)(best & 0xffffffffu);
    }
}

// ---------------- fallback: f32 VALU path ------------------------------------------
constexpr int FCH = 8;
constexpr int FMC = M_ / FCH;

__global__ __launch_bounds__(256) void pwd_chunk(
        const float* __restrict__ p, const float* __restrict__ pn,
        const float* __restrict__ c, const float* __restrict__ c_sq,
        unsigned long long* __restrict__ ws) {
    const int n = blockIdx.x * 256 + threadIdx.x;
    const int mbase = blockIdx.y * FMC;
    float prr[D_];
    const float4* p4 = reinterpret_cast<const float4*>(p + (size_t)n * D_);
#pragma unroll
    for (int i = 0; i < D_ / 4; ++i) {
        float4 v = p4[i];
        prr[4*i+0] = v.x; prr[4*i+1] = v.y; prr[4*i+2] = v.z; prr[4*i+3] = v.w;
    }
    const float pnn = pn[n];
    float bestD = INFINITY;
    int   bestM = mbase;
#pragma unroll 2
    for (int mi = 0; mi < FMC; ++mi) {
        const int m = mbase + mi;
        const float* cm = c + (size_t)m * D_;
        float a0 = 0.f, a1 = 0.f, a2 = 0.f, a3 = 0.f;
#pragma unroll
        for (int k = 0; k < D_; k += 4) {
            a0 = fmaf(prr[k+0], cm[k+0], a0);
            a1 = fmaf(prr[k+1], cm[k+1], a1);
            a2 = fmaf(prr[k+2], cm[k+2], a2);
            a3 = fmaf(prr[k+3], cm[k+3], a3);
        }
        const float dot  = (a0 + a1) + (a2 + a3);
        const float dist = fmaf(-2.f, dot, pnn + c_sq[m]);
        if (dist < bestD) { bestD = dist; bestM = m; }
    }
    atomicMin(&ws[n], pack_dl(bestD, (unsigned)bestM));
}

__global__ __launch_bounds__(256) void pwd_out(
        const unsigned long long* __restrict__ results, float* __restrict__ out) {
    const int n = blockIdx.x * 256 + threadIdx.x;
    const unsigned long long v = results[n];
    out[n]      = __uint_as_float((unsigned)(v >> 32));
    out[N_ + n] = (float)(unsigned)(v & 0xffffffffu);
}

extern "C" void kernel_launch(void* const* d_in, const int* in_sizes, int n_in,
                              void* d_out, int out_size, void* d_ws, size_t ws_size,
                              hipStream_t stream) {
    const float* p    = (const float*)d_in[0];
    const float* pn   = (const float*)d_in[1];
    const float* c    = (const float*)d_in[2];
    const float* c_sq = (const float*)d_in[3];
    float* out = (float*)d_out;

    char* ws = (char*)d_ws;
    const size_t off_phi  = 0;
    const size_t off_chi  = (size_t)N_ * D_ * 2;                 // 8 MB
    const size_t off_nhc  = off_chi + (size_t)M_ * D_ * 2;       // +512 KB
    const size_t off_cand = off_nhc + (size_t)M_ * 4;            // +16 KB
    const size_t need     = off_cand + (size_t)N_ * 32 * 2;      // +4 MB

    if (ws_size >= need) {
        unsigned short* Phi   = (unsigned short*)(ws + off_phi);
        unsigned short* ChiT  = (unsigned short*)(ws + off_chi);
        float*          nhcsq = (float*)(ws + off_nhc);
        unsigned short* cand  = (unsigned short*)(ws + off_cand);

        constexpr int PREP_T = N_ * D_ / 8 + M_ * D_ / 8 + M_;
        pwd_prep<<<(PREP_T + 255) / 256, 256, 0, stream>>>(p, c, c_sq, Phi, ChiT, nhcsq);
        dim3 sgrid(N_ / 128, 2);
        pwd_scan<<<sgrid, 256, 0, stream>>>(Phi, ChiT, nhcsq, cand);
        pwd_exact<<<(N_ * 4) / 256, 256, 0, stream>>>(p, pn, c, c_sq, cand, out);
    } else if (ws_size >= (size_t)N_ * 8) {
        unsigned long long* results = (unsigned long long*)ws;
        hipMemsetAsync(ws, 0xFF, (size_t)N_ * 8, stream);
        dim3 grid(N_ / 256, FCH);
        pwd_chunk<<<grid, 256, 0, stream>>>(p, pn, c, c_sq, results);
        pwd_out<<<N_ / 256, 256, 0, stream>>>(results, out);
    }
}